// Round 16
// baseline (156.036 us; speedup 1.0000x reference)
//
#include <hip/hip_runtime.h>

constexpr int Ln = 32, Dn = 128, Hn = 8;

using bf16x8 = __attribute__((ext_vector_type(8))) short;
using f32x4  = __attribute__((ext_vector_type(4))) float;

__device__ __forceinline__ unsigned short f2bf(float f) {
    union { float f; unsigned u; } v; v.f = f;
    unsigned r = v.u + 0x7FFFu + ((v.u >> 16) & 1u);
    return (unsigned short)(r >> 16);
}
__device__ __forceinline__ float bf2f(unsigned short s) {
    union { unsigned u; float f; } v; v.u = ((unsigned)s) << 16; return v.f;
}
__device__ __forceinline__ bf16x8 cvt8(float4 a, float4 b) {
    bf16x8 r;
    r[0] = (short)f2bf(a.x); r[1] = (short)f2bf(a.y);
    r[2] = (short)f2bf(a.z); r[3] = (short)f2bf(a.w);
    r[4] = (short)f2bf(b.x); r[5] = (short)f2bf(b.y);
    r[6] = (short)f2bf(b.z); r[7] = (short)f2bf(b.w);
    return r;
}

// ---- ws layout (shorts) ----
// wq0b @0 (131072, *scale) | wq1b @131072 (131072, *scale) | wv0b @262144 (16384)
// wp0b @278528 (16384) | wv1b @294912 (131072, *0.125) | wp1b @425984 (16384)
// f32 @ short-offset 442368: bq0s[1024]*scale, bq1s[1024]*scale, b0[128]=bp0+bv0,
//                            b1[128]=bp1+0.125*sum_h bv1
constexpr int    CVT_ITEMS = 442368 + 2304;
constexpr size_t WS_NEED   = 442368ull * 2 + 2304ull * 4;

__global__ void cvt_weights(const float* __restrict__ wq0, const float* __restrict__ bq0,
                            const float* __restrict__ wv0, const float* __restrict__ bv0,
                            const float* __restrict__ wp0, const float* __restrict__ bp0,
                            const float* __restrict__ wq1, const float* __restrict__ bq1,
                            const float* __restrict__ wv1, const float* __restrict__ bv1,
                            const float* __restrict__ wp1, const float* __restrict__ bp1,
                            unsigned short* __restrict__ ws)
{
    const float scale = 0.08838834764831845f;  // 1/sqrt(128)
    int tid = blockIdx.x * 256 + threadIdx.x;
    if (tid >= CVT_ITEMS) return;
    if (tid < 442368) {
        float v;
        if      (tid < 131072) v = wq0[tid] * scale;
        else if (tid < 262144) v = wq1[tid - 131072] * scale;
        else if (tid < 278528) v = wv0[tid - 262144];
        else if (tid < 294912) v = wp0[tid - 278528];
        else if (tid < 425984) v = wv1[tid - 294912] * 0.125f;
        else                   v = wp1[tid - 425984];
        ws[tid] = f2bf(v);
    } else {
        int j = tid - 442368;
        float* fws = (float*)(ws + 442368);
        if      (j < 1024) fws[j] = bq0[j] * scale;
        else if (j < 2048) fws[j] = bq1[j - 1024] * scale;
        else if (j < 2176) { int d = j - 2048; fws[j] = bp0[d] + bv0[d]; }
        else if (j < 2304) {
            int d = j - 2176;
            float s = 0.f;
            #pragma unroll
            for (int h = 0; h < Hn; ++h) s += bv1[h * Dn + d];
            fws[j] = bp1[d] + 0.125f * s;
        }
    }
}

// ============ gcn16: 20 waves/CU -- 8 nodes / 256 threads / 1024 blocks ===========
// LDS 31.8 KB -> 5 resident blocks/CU (20 waves, 5 independent barrier domains),
// vs gcn15's 2 blocks/16 waves. Attention uses 8-row quarter-slots: up to 4
// sub-tiles per node, each {stage, QK(M=16, rows>=8 masked), partial exp/sum,
// PV}; sums accumulate directly (no max-subtraction => no rescale needed).
// MFMA M-rows 8-15 are padding everywhere (sX rows 8-15 kept zero; sQC/sN
// over-reads land in valid LDS and are discarded by write guards).
__global__ __launch_bounds__(256, 5)
void gcn16(const float* __restrict__ nodeE, const float* __restrict__ neighE,
           const int* __restrict__ degp, const unsigned short* __restrict__ ws,
           float* __restrict__ out)
{
    __shared__ unsigned short sN[4][8][136];    // per-wave QUARTER slot        8704 B
    __shared__ unsigned short sQC[8 * 1096];    // q then c, [n*1096+h*136+d]  17536 B
    __shared__ unsigned short sX[16][136];      // 8 nodes + 8 zero rows        4352 B
    __shared__ float          sP[4][8][Hn];     // p (unnorm) [wave][slot_l][h] 1024 B
    __shared__ float          sSum[4][Hn];      // per-head sums [wave][h]       128 B
    __shared__ int            sDeg[8];          //                                32 B

    const unsigned short* wq0b = ws;
    const unsigned short* wq1b = ws + 131072;
    const unsigned short* wv0b = ws + 262144;
    const unsigned short* wp0b = ws + 278528;
    const unsigned short* wv1b = ws + 294912;
    const unsigned short* wp1b = ws + 425984;
    const float* fws  = (const float*)(ws + 442368);
    const float* bq0s = fws;
    const float* bq1s = fws + 1024;
    const float* b0   = fws + 2048;
    const float* b1   = fws + 2176;

    const int t    = threadIdx.x;
    const int lane = t & 63;
    const int w    = t >> 6;       // wave id 0..3
    const int row  = lane & 15;
    const int kg   = lane >> 4;
    const int node0 = blockIdx.x * 8;

    bf16x8 a[4];                   // x fragment, loaded in qgemm, reused in ep

    // wave-private: stage rows [r0, r0+v) of 'node' (v <= 8) into slot rows [0, v)
    auto stage_q = [&](int node, int r0, int v) {
        const float* base = neighE + ((size_t)(node0 + node) * Ln + r0) * Dn;
        #pragma unroll
        for (int it = 0; it < 2; ++it) {
            int c = lane + 64 * it;               // 128 chunks: 8 rows x 16 x 8 floats
            int l = c >> 4, d8 = c & 15;
            if (l < v) {
                const float4* s = (const float4*)(base + (size_t)c * 8);
                *(bf16x8*)&sN[w][l][d8 * 8] = cvt8(s[0], s[1]);
            }
        }
    };

    auto qgemm = [&](const unsigned short* wqb, const float* bqs) {
        #pragma unroll
        for (int ks = 0; ks < 4; ++ks)
            a[ks] = *(const bf16x8*)&sX[row][ks * 32 + kg * 8];
        #pragma unroll
        for (int f = 0; f < 16; ++f) {
            int o = w * 256 + f * 16 + row;       // wave w covers o in [256w, 256w+256)
            f32x4 acc = {0.f, 0.f, 0.f, 0.f};
            #pragma unroll
            for (int ks = 0; ks < 4; ++ks)
                acc = __builtin_amdgcn_mfma_f32_16x16x32_bf16(
                    a[ks], *(const bf16x8*)(wqb + (size_t)o * Dn + ks * 32 + kg * 8), acc, 0, 0, 0);
            float bias = bqs[o];
            int h = o >> 7, d = o & 127;
            if (kg < 2) {                         // nodes = M-rows 0..7 only
                #pragma unroll
                for (int rr = 0; rr < 4; ++rr)
                    sQC[(kg * 4 + rr) * 1096 + h * 136 + d] = f2bf(acc[rr] + bias);
            }
        }
    };

    // PV accumulate over slot rows [0, v) into c
    auto pv_acc = [&](float (&c)[Hn][2], int v) {
        #pragma unroll 2
        for (int l = 0; l < v; ++l) {
            unsigned nv = *(const unsigned*)&sN[w][l][2 * lane];
            float n0 = bf2f((unsigned short)(nv & 0xFFFFu));
            float n1 = bf2f((unsigned short)(nv >> 16));
            float4 p01 = *(const float4*)&sP[w][l][0];
            float4 p23 = *(const float4*)&sP[w][l][4];
            c[0][0] += p01.x * n0; c[0][1] += p01.x * n1;
            c[1][0] += p01.y * n0; c[1][1] += p01.y * n1;
            c[2][0] += p01.z * n0; c[2][1] += p01.z * n1;
            c[3][0] += p01.w * n0; c[3][1] += p01.w * n1;
            c[4][0] += p23.x * n0; c[4][1] += p23.x * n1;
            c[5][0] += p23.y * n0; c[5][1] += p23.y * n1;
            c[6][0] += p23.z * n0; c[6][1] += p23.z * n1;
            c[7][0] += p23.w * n0; c[7][1] += p23.w * n1;
        }
    };

    // 4-sub-tile attention (wave-private, no max-subtraction, per-head sums).
    // QK A-operand reads slot rows 0..15; rows >= 8 overrun into adjacent LDS
    // (valid memory, garbage values) and are masked before use (l < v).
    auto attn4 = [&](int node) {
        const int deg = sDeg[node];
        const int hcol = row & 7;
        bf16x8 qf[4];
        #pragma unroll
        for (int ks = 0; ks < 4; ++ks)
            qf[ks] = *(const bf16x8*)&sQC[node * 1096 + hcol * 136 + ks * 32 + kg * 8];

        float sum = 0.f;                           // per-head (lane's column) sum
        float c[Hn][2];
        #pragma unroll
        for (int h = 0; h < Hn; ++h) { c[h][0] = 0.f; c[h][1] = 0.f; }

        #pragma unroll
        for (int tt = 0; tt < 4; ++tt) {
            int r0 = tt * 8;
            if (r0 < deg) {                        // wave-uniform
                int v = deg - r0; v = v < 8 ? v : 8;
                stage_q(node, r0, v);
                f32x4 s0 = {0.f,0.f,0.f,0.f};
                __builtin_amdgcn_s_setprio(1);
                #pragma unroll
                for (int ks = 0; ks < 4; ++ks)
                    s0 = __builtin_amdgcn_mfma_f32_16x16x32_bf16(
                        *(const bf16x8*)&sN[w][row][ks * 32 + kg * 8], qf[ks], s0, 0, 0, 0);
                __builtin_amdgcn_s_setprio(0);
                float sv[4];
                float ps = 0.f;
                #pragma unroll
                for (int j = 0; j < 4; ++j) {
                    int l = kg * 4 + j;
                    sv[j] = (l < v) ? __expf(s0[j]) : 0.f;
                    ps += sv[j];
                }
                ps += __shfl_xor(ps, 16);
                ps += __shfl_xor(ps, 32);
                sum += ps;
                if (row < 8 && kg < 2) {           // slot_l = kg*4+j in [0,8)
                    #pragma unroll
                    for (int j = 0; j < 4; ++j)
                        sP[w][kg * 4 + j][row] = sv[j];
                }
                pv_acc(c, v);
            }
        }

        // broadcast per-head sums; normalize each c[h] by ITS head's sum
        if (row < 8) sSum[w][row] = sum;           // 4 dup lanes write same value
        float4 r01 = *(const float4*)&sSum[w][0];
        float4 r23 = *(const float4*)&sSum[w][4];
        float rh[Hn] = {r01.x, r01.y, r01.z, r01.w, r23.x, r23.y, r23.z, r23.w};
        #pragma unroll
        for (int h = 0; h < Hn; ++h) {
            float inv = 1.f / rh[h];
            unsigned pk = (unsigned)f2bf(c[h][0] * inv) | ((unsigned)f2bf(c[h][1] * inv) << 16);
            *(unsigned*)&sQC[node * 1096 + h * 136 + 2 * lane] = pk;
        }
    };

    // ---- prologue: 8 node rows + 8 zero rows (MFMA M-padding), degs ----
    {
        int r = t >> 4, c = (t & 15) * 8;          // 16 rows x 16 chunks
        bf16x8 v;
        if (r < 8) {
            const float4* s = (const float4*)(nodeE + (size_t)(node0 + r) * Dn + c);
            v = cvt8(s[0], s[1]);
        } else {
            bf16x8 z = {0,0,0,0,0,0,0,0}; v = z;
        }
        *(bf16x8*)&sX[r][c] = v;
    }
    if (t < 8) sDeg[t] = degp[node0 + t];
    __syncthreads();

    // ======== layer 0 ========
    qgemm(wq0b, bq0s);
    __syncthreads();            // q visible

    attn4(w);                   // nodes 0..3 (wave-private, no barriers)
    attn4(4 + w);               // nodes 4..7
    __syncthreads();            // all c0 visible

    {   // ---- ep0: x1 = relu(x@wp0.T + c[h(d)]@wv0.T + b0); wave w owns d in [32w,32w+32)
        float xn[2][4]; int dd[2];
        #pragma unroll
        for (int fi = 0; fi < 2; ++fi) {
            const int h = 2 * w + fi;
            const int d = h * 16 + row; dd[fi] = d;
            f32x4 pa = {0.f,0.f,0.f,0.f}, va = {0.f,0.f,0.f,0.f};
            #pragma unroll
            for (int ks = 0; ks < 4; ++ks) {
                pa = __builtin_amdgcn_mfma_f32_16x16x32_bf16(
                    a[ks], *(const bf16x8*)(wp0b + (size_t)d * Dn + ks * 32 + kg * 8), pa, 0, 0, 0);
                // A-operand rows 8..15 read past node 7's region (valid LDS,
                // garbage) -> their output rows are discarded by the kg<2 guard.
                bf16x8 c0 = *(const bf16x8*)&sQC[row * 1096 + h * 136 + ks * 32 + kg * 8];
                va = __builtin_amdgcn_mfma_f32_16x16x32_bf16(
                    c0, *(const bf16x8*)(wv0b + (size_t)d * Dn + ks * 32 + kg * 8), va, 0, 0, 0);
            }
            float bias = b0[d];
            #pragma unroll
            for (int rr = 0; rr < 4; ++rr)
                xn[fi][rr] = fmaxf(pa[rr] + va[rr] + bias, 0.f);
        }
        if (kg < 2) {                              // nodes 0..7; rows 8-15 stay zero
            #pragma unroll
            for (int fi = 0; fi < 2; ++fi)
                #pragma unroll
                for (int rr = 0; rr < 4; ++rr)
                    sX[kg * 4 + rr][dd[fi]] = f2bf(xn[fi][rr]);
        }
    }
    __syncthreads();            // new x visible

    // ======== layer 1 ========
    qgemm(wq1b, bq1s);
    __syncthreads();

    attn4(w);
    attn4(4 + w);
    __syncthreads();            // all c1 visible

    {   // ---- ep1: out = x1@wp1.T + (cflat@wv1'.T) + b1 (0.125 folded in wv1b/b1)
        const int d0 = w * 32 + row;               // h = 2w
        const int d1 = d0 + 16;                    // h = 2w+1
        f32x4 p0 = {0.f,0.f,0.f,0.f}, p1 = {0.f,0.f,0.f,0.f};
        #pragma unroll
        for (int ks = 0; ks < 4; ++ks) {
            p0 = __builtin_amdgcn_mfma_f32_16x16x32_bf16(
                a[ks], *(const bf16x8*)(wp1b + (size_t)d0 * Dn + ks * 32 + kg * 8), p0, 0, 0, 0);
            p1 = __builtin_amdgcn_mfma_f32_16x16x32_bf16(
                a[ks], *(const bf16x8*)(wp1b + (size_t)d1 * Dn + ks * 32 + kg * 8), p1, 0, 0, 0);
        }
        f32x4 g0 = {0.f,0.f,0.f,0.f}, g1 = {0.f,0.f,0.f,0.f};
        #pragma unroll 8
        for (int ks2 = 0; ks2 < 32; ++ks2) {       // K = 1024 over hk; c reused for both d
            int hk = ks2 * 32 + kg * 8;
            int h = hk >> 7, kk = hk & 127;
            bf16x8 c0 = *(const bf16x8*)&sQC[row * 1096 + h * 136 + kk];
            g0 = __builtin_amdgcn_mfma_f32_16x16x32_bf16(
                c0, *(const bf16x8*)(wv1b + ((size_t)(h * Dn + d0)) * Dn + kk), g0, 0, 0, 0);
            g1 = __builtin_amdgcn_mfma_f32_16x16x32_bf16(
                c0, *(const bf16x8*)(wv1b + ((size_t)(h * Dn + d1)) * Dn + kk), g1, 0, 0, 0);
        }
        if (kg < 2) {                              // nodes 0..7
            #pragma unroll
            for (int rr = 0; rr < 4; ++rr) {
                out[(size_t)(node0 + kg * 4 + rr) * Dn + d0] = p0[rr] + g0[rr] + b1[d0];
                out[(size_t)(node0 + kg * 4 + rr) * Dn + d1] = p1[rr] + g1[rr] + b1[d1];
            }
        }
    }
}

// ================= fallback (ws-independent raw-pointer kernel) ===================
__global__ __launch_bounds__(256, 2)
void gcn2(const float* __restrict__ nodeE, const float* __restrict__ neighE,
          const int* __restrict__ degp,
          const float* __restrict__ wq0, const float* __restrict__ bq0,
          const float* __restrict__ wv0, const float* __restrict__ bv0,
          const float* __restrict__ wp0, const float* __restrict__ bp0,
          const float* __restrict__ wq1, const float* __restrict__ bq1,
          const float* __restrict__ wv1, const float* __restrict__ bv1,
          const float* __restrict__ wp1, const float* __restrict__ bp1,
          float* __restrict__ out)
{
    __shared__ unsigned short sX[16][Dn];
    __shared__ unsigned short sQ[8][Hn][Dn];
    __shared__ unsigned short sN[4][Ln][Dn + 8];
    __shared__ float          sP[4][Hn][Ln];
    __shared__ unsigned short sC[8][Hn][Dn + 8];
    __shared__ int            sDeg[8];

    const int t    = threadIdx.x;
    const int lane = t & 63;
    const int w    = t >> 6;
    const int row  = lane & 15;
    const int kg   = lane >> 4;
    const int node0 = blockIdx.x * 8;
    const float scale = 0.08838834764831845f;

    {
        int i = t * 8, r = i >> 7, c = i & 127;
        if (r < 8) {
            const float4* s = (const float4*)(nodeE + (size_t)(node0 + r) * Dn + c);
            *(bf16x8*)&sX[r][c] = cvt8(s[0], s[1]);
        } else {
            bf16x8 z = {0,0,0,0,0,0,0,0};
            *(bf16x8*)&sX[r][c] = z;
        }
        if (t < 8) sDeg[t] = degp[node0 + t];
    }
    __syncthreads();

    auto qgemm = [&](const float* wq, const float* bq) {
        bf16x8 a[4];
        #pragma unroll
        for (int ks = 0; ks < 4; ++ks)
            a[ks] = *(const bf16x8*)&sX[row][ks*32 + kg*8];
        for (int f = 0; f < 16; ++f) {
            int o = w*256 + f*16 + row;
            f32x4 acc = {0.f, 0.f, 0.f, 0.f};
            #pragma unroll
            for (int ks = 0; ks < 4; ++ks) {
                const float4* wp4 = (const float4*)(wq + (size_t)o*Dn + ks*32 + kg*8);
                acc = __builtin_amdgcn_mfma_f32_16x16x32_bf16(a[ks], cvt8(wp4[0], wp4[1]), acc, 0, 0, 0);
            }
            float bias = bq[o];
            if (kg < 2) {
                #pragma unroll
                for (int rr = 0; rr < 4; ++rr) {
                    int nd = kg*4 + rr;
                    sQ[nd][o >> 7][o & 127] = f2bf((acc[rr] + bias) * scale);
                }
            }
        }
    };

    auto attn = [&](int b) {
        #pragma unroll
        for (int it = 0; it < 8; ++it) {
            int e8 = t + 256 * it;
            int n = e8 >> 9, l = (e8 >> 4) & 31, d8 = e8 & 15;
            const float4* s = (const float4*)(neighE + ((size_t)(node0 + b*4 + n)*Ln + l)*Dn + d8*8);
            *(bf16x8*)&sN[n][l][d8*8] = cvt8(s[0], s[1]);
        }
        __syncthreads();

        const int deg  = sDeg[b*4 + w];
        const int hcol = row & 7;
        bf16x8 qf[4];
        #pragma unroll
        for (int ks = 0; ks < 4; ++ks)
            qf[ks] = *(const bf16x8*)&sQ[b*4 + w][hcol][ks*32 + kg*8];

        f32x4 s0 = {0.f,0.f,0.f,0.f}, s1 = {0.f,0.f,0.f,0.f};
        #pragma unroll
        for (int ks = 0; ks < 4; ++ks) {
            bf16x8 a0 = *(const bf16x8*)&sN[w][row][ks*32 + kg*8];
            bf16x8 a1 = *(const bf16x8*)&sN[w][16 + row][ks*32 + kg*8];
            s0 = __builtin_amdgcn_mfma_f32_16x16x32_bf16(a0, qf[ks], s0, 0, 0, 0);
            s1 = __builtin_amdgcn_mfma_f32_16x16x32_bf16(a1, qf[ks], s1, 0, 0, 0);
        }
        float sv[8];
        #pragma unroll
        for (int rr = 0; rr < 4; ++rr) { sv[rr] = s0[rr]; sv[4+rr] = s1[rr]; }
        float m = -3.0e38f;
        #pragma unroll
        for (int j = 0; j < 8; ++j) {
            int l = (j >> 2)*16 + kg*4 + (j & 3);
            if (l >= deg) sv[j] = -3.0e38f;
            m = fmaxf(m, sv[j]);
        }
        m = fmaxf(m, __shfl_xor(m, 16));
        m = fmaxf(m, __shfl_xor(m, 32));
        float sum = 0.f;
        #pragma unroll
        for (int j = 0; j < 8; ++j) {
            float e = (sv[j] > -1.0e38f) ? __expf(sv[j] - m) : 0.f;
            sv[j] = e; sum += e;
        }
        sum += __shfl_xor(sum, 16);
        sum += __shfl_xor(sum, 32);
        float rinv = 1.f / sum;
        if (row < 8) {
            #pragma unroll
            for (int j = 0; j < 8; ++j) {
                int l = (j >> 2)*16 + kg*4 + (j & 3);
                sP[w][row][l] = sv[j] * rinv;
            }
        }

        float c[Hn][2];
        #pragma unroll
        for (int h = 0; h < Hn; ++h) { c[h][0] = 0.f; c[h][1] = 0.f; }
        #pragma unroll 4
        for (int l = 0; l < Ln; ++l) {
            unsigned nv = *(const unsigned*)&sN[w][l][2*lane];
            float n0 = bf2f((unsigned short)(nv & 0xFFFFu));
            float n1 = bf2f((unsigned short)(nv >> 16));
            #pragma unroll
            for (int h = 0; h < Hn; ++h) {
                float p = sP[w][h][l];
                c[h][0] += p * n0; c[h][1] += p * n1;
            }
        }
        #pragma unroll
        for (int h = 0; h < Hn; ++h) {
            unsigned pk = (unsigned)f2bf(c[h][0]) | ((unsigned)f2bf(c[h][1]) << 16);
            *(unsigned*)&sC[b*4 + w][h][2*lane] = pk;
        }
        __syncthreads();
    };

    auto ep0 = [&]() {
        bf16x8 a1[4];
        #pragma unroll
        for (int ks = 0; ks < 4; ++ks)
            a1[ks] = *(const bf16x8*)&sX[row][ks*32 + kg*8];
        float xn[2][4]; int dd[2];
        #pragma unroll
        for (int fi = 0; fi < 2; ++fi) {
            int f = 2*w + fi;
            int d = f*16 + row; dd[fi] = d;
            f32x4 acc = {0.f,0.f,0.f,0.f}, acc2 = {0.f,0.f,0.f,0.f};
            #pragma unroll
            for (int ks = 0; ks < 4; ++ks) {
                const float4* bp = (const float4*)(wp0 + (size_t)d*Dn + ks*32 + kg*8);
                acc = __builtin_amdgcn_mfma_f32_16x16x32_bf16(a1[ks], cvt8(bp[0], bp[1]), acc, 0, 0, 0);
                bf16x8 a2 = *(const bf16x8*)&sC[row & 7][f][ks*32 + kg*8];
                const float4* vp = (const float4*)(wv0 + (size_t)d*Dn + ks*32 + kg*8);
                acc2 = __builtin_amdgcn_mfma_f32_16x16x32_bf16(a2, cvt8(vp[0], vp[1]), acc2, 0, 0, 0);
            }
            float bias = bp0[d] + bv0[d];
            #pragma unroll
            for (int rr = 0; rr < 4; ++rr)
                xn[fi][rr] = fmaxf(acc[rr] + acc2[rr] + bias, 0.f);
        }
        __syncthreads();
        if (kg < 2) {
            #pragma unroll
            for (int fi = 0; fi < 2; ++fi)
                #pragma unroll
                for (int rr = 0; rr < 4; ++rr)
                    sX[kg*4 + rr][dd[fi]] = f2bf(xn[fi][rr]);
        }
        __syncthreads();
    };

    auto ep1 = [&]() {
        bf16x8 a1[4];
        #pragma unroll
        for (int ks = 0; ks < 4; ++ks)
            a1[ks] = *(const bf16x8*)&sX[row][ks*32 + kg*8];
        #pragma unroll
        for (int fi = 0; fi < 2; ++fi) {
            int f = 2*w + fi;
            int d = f*16 + row;
            f32x4 acc = {0.f,0.f,0.f,0.f};
            #pragma unroll
            for (int ks = 0; ks < 4; ++ks) {
                const float4* bp = (const float4*)(wp1 + (size_t)d*Dn + ks*32 + kg*8);
                acc = __builtin_amdgcn_mfma_f32_16x16x32_bf16(a1[ks], cvt8(bp[0], bp[1]), acc, 0, 0, 0);
            }
            f32x4 acc2 = {0.f,0.f,0.f,0.f};
            for (int ks2 = 0; ks2 < 32; ++ks2) {
                int hk = ks2*32 + kg*8;
                int h = hk >> 7, kk = hk & 127;
                bf16x8 a2 = *(const bf16x8*)&sC[row & 7][h][kk];
                const float4* vp = (const float4*)(wv1 + ((size_t)(h*Dn + d))*Dn + kk);
                acc2 = __builtin_amdgcn_mfma_f32_16x16x32_bf16(a2, cvt8(vp[0], vp[1]), acc2, 0, 0, 0);
            }
            float bsum = 0.f;
            #pragma unroll
            for (int h = 0; h < Hn; ++h) bsum += bv1[h*Dn + d];
            float bias = bp1[d] + 0.125f * bsum;
            if (kg < 2) {
                #pragma unroll
                for (int rr = 0; rr < 4; ++rr) {
                    int nd = kg*4 + rr;
                    out[(size_t)(node0 + nd)*Dn + d] = acc[rr] + 0.125f*acc2[rr] + bias;
                }
            }
        }
    };

    qgemm(wq0, bq0);
    __syncthreads();
    attn(0);
    attn(1);
    ep0();
    qgemm(wq1, bq1);
    __syncthreads();
    attn(0);
    attn(1);
    ep1();
}

extern "C" void kernel_launch(void* const* d_in, const int* in_sizes, int n_in,
                              void* d_out, int out_size, void* d_ws, size_t ws_size,
                              hipStream_t stream) {
    const float* nodeE  = (const float*)d_in[0];
    const float* neighE = (const float*)d_in[1];
    const int*   degp   = (const int*)d_in[2];
    const float* wq0 = (const float*)d_in[3];
    const float* bq0 = (const float*)d_in[4];
    const float* wv0 = (const float*)d_in[5];
    const float* bv0 = (const float*)d_in[6];
    const float* wp0 = (const float*)d_in[7];
    const float* bp0 = (const float*)d_in[8];
    const float* wq1 = (const float*)d_in[9];
    const float* bq1 = (const float*)d_in[10];
    const float* wv1 = (const float*)d_in[11];
    const float* bv1 = (const float*)d_in[12];
    const float* wp1 = (const float*)d_in[13];
    const float* bp1 = (const float*)d_in[14];
    float* outp = (float*)d_out;

    if (ws_size >= WS_NEED) {
        unsigned short* ws = (unsigned short*)d_ws;
        hipLaunchKernelGGL(cvt_weights, dim3((CVT_ITEMS + 255) / 256), dim3(256), 0, stream,
                           wq0, bq0, wv0, bv0, wp0, bp0,
                           wq1, bq1, wv1, bv1, wp1, bp1, ws);
        hipLaunchKernelGGL(gcn16, dim3(1024), dim3(256), 0, stream,
                           nodeE, neighE, degp, ws, outp);
    } else {
        hipLaunchKernelGGL(gcn2, dim3(1024), dim3(256), 0, stream,
                           nodeE, neighE, degp,
                           wq0, bq0, wv0, bv0, wp0, bp0,
                           wq1, bq1, wv1, bv1, wp1, bp1, outp);
    }
}

// Round 17
// 83.240 us; speedup vs baseline: 1.8745x; 1.8745x over previous
//
#include <hip/hip_runtime.h>

constexpr int Ln = 32, Dn = 128, Hn = 8;

using bf16x8 = __attribute__((ext_vector_type(8))) short;
using f32x4  = __attribute__((ext_vector_type(4))) float;

__device__ __forceinline__ unsigned short f2bf(float f) {
    union { float f; unsigned u; } v; v.f = f;
    unsigned r = v.u + 0x7FFFu + ((v.u >> 16) & 1u);
    return (unsigned short)(r >> 16);
}
__device__ __forceinline__ float bf2f(unsigned short s) {
    union { unsigned u; float f; } v; v.u = ((unsigned)s) << 16; return v.f;
}
__device__ __forceinline__ bf16x8 cvt8(float4 a, float4 b) {
    bf16x8 r;
    r[0] = (short)f2bf(a.x); r[1] = (short)f2bf(a.y);
    r[2] = (short)f2bf(a.z); r[3] = (short)f2bf(a.w);
    r[4] = (short)f2bf(b.x); r[5] = (short)f2bf(b.y);
    r[6] = (short)f2bf(b.z); r[7] = (short)f2bf(b.w);
    return r;
}

// ---- ws layout (shorts) ----
// wq0b @0 (131072, *scale) | wq1b @131072 (131072, *scale) | wv0b @262144 (16384)
// wp0b @278528 (16384) | wv1b @294912 (131072, *0.125) | wp1b @425984 (16384)
// f32 @ short-offset 442368: bq0s[1024]*scale, bq1s[1024]*scale, b0[128]=bp0+bv0,
//                            b1[128]=bp1+0.125*sum_h bv1
constexpr int    CVT_ITEMS = 442368 + 2304;
constexpr size_t WS_NEED   = 442368ull * 2 + 2304ull * 4;

__global__ void cvt_weights(const float* __restrict__ wq0, const float* __restrict__ bq0,
                            const float* __restrict__ wv0, const float* __restrict__ bv0,
                            const float* __restrict__ wp0, const float* __restrict__ bp0,
                            const float* __restrict__ wq1, const float* __restrict__ bq1,
                            const float* __restrict__ wv1, const float* __restrict__ bv1,
                            const float* __restrict__ wp1, const float* __restrict__ bp1,
                            unsigned short* __restrict__ ws)
{
    const float scale = 0.08838834764831845f;  // 1/sqrt(128)
    int tid = blockIdx.x * 256 + threadIdx.x;
    if (tid >= CVT_ITEMS) return;
    if (tid < 442368) {
        float v;
        if      (tid < 131072) v = wq0[tid] * scale;
        else if (tid < 262144) v = wq1[tid - 131072] * scale;
        else if (tid < 278528) v = wv0[tid - 262144];
        else if (tid < 294912) v = wp0[tid - 278528];
        else if (tid < 425984) v = wv1[tid - 294912] * 0.125f;
        else                   v = wp1[tid - 425984];
        ws[tid] = f2bf(v);
    } else {
        int j = tid - 442368;
        float* fws = (float*)(ws + 442368);
        if      (j < 1024) fws[j] = bq0[j] * scale;
        else if (j < 2048) fws[j] = bq1[j - 1024] * scale;
        else if (j < 2176) { int d = j - 2048; fws[j] = bp0[d] + bv0[d]; }
        else if (j < 2304) {
            int d = j - 2176;
            float s = 0.f;
            #pragma unroll
            for (int h = 0; h < Hn; ++h) s += bv1[h * Dn + d];
            fws[j] = bp1[d] + 0.125f * s;
        }
    }
}

// ============ gcn15: session-best (83.5 us verified) ==============================
// 16 nodes / 512 threads / 512 blocks, LDS 78.8 KB -> 2 resident blocks/CU
// (16 waves). 2-tile deg-gated attention, no max-subtraction (softmax is
// shift-invariant; |scores| small), per-head sums broadcast via sSum. setprio
// around attn QK MFMAs; PV loop unroll 2. All register state intra-phase
// (register-buffer prefetch spilled to scratch in 4 prior attempts; finer
// tiling for >16 waves regressed 2x -- this is the measured optimum).
__global__ __launch_bounds__(512, 4)
void gcn15(const float* __restrict__ nodeE, const float* __restrict__ neighE,
           const int* __restrict__ degp, const unsigned short* __restrict__ ws,
           float* __restrict__ out)
{
    __shared__ unsigned short sN[8][16][136];   // per-wave HALF slot          34816 B
    __shared__ unsigned short sQC[16 * 1096];   // q then c, [n*1096+h*136+d]  35072 B
    __shared__ unsigned short sX[16][136];      // 16 node embeds               4352 B
    __shared__ float          sP[8][16][Hn];    // p (unnorm) [wave][slot_l][h] 4096 B
    __shared__ float          sSum[8][Hn];      // per-head sums [wave][h]       256 B
    __shared__ int            sDeg[16];         //                                64 B

    const unsigned short* wq0b = ws;
    const unsigned short* wq1b = ws + 131072;
    const unsigned short* wv0b = ws + 262144;
    const unsigned short* wp0b = ws + 278528;
    const unsigned short* wv1b = ws + 294912;
    const unsigned short* wp1b = ws + 425984;
    const float* fws  = (const float*)(ws + 442368);
    const float* bq0s = fws;
    const float* bq1s = fws + 1024;
    const float* b0   = fws + 2048;
    const float* b1   = fws + 2176;

    const int t    = threadIdx.x;
    const int lane = t & 63;
    const int w    = t >> 6;       // wave id 0..7
    const int row  = lane & 15;
    const int kg   = lane >> 4;
    const int node0 = blockIdx.x * 16;

    bf16x8 a[4];                   // x fragment, loaded in qgemm, reused in ep

    // wave-private: stage rows [r0, r0+v) of 'node' into slot rows [0, v)
    auto stage_half = [&](int node, int r0, int v) {
        const float* base = neighE + ((size_t)(node0 + node) * Ln + r0) * Dn;
        #pragma unroll
        for (int it = 0; it < 4; ++it) {
            int c = lane + 64 * it;               // 256 chunks: 16 rows x 16 x 8 floats
            int l = c >> 4, d8 = c & 15;
            if (l < v) {
                const float4* s = (const float4*)(base + (size_t)c * 8);
                *(bf16x8*)&sN[w][l][d8 * 8] = cvt8(s[0], s[1]);
            }
        }
    };

    auto qgemm = [&](const unsigned short* wqb, const float* bqs) {
        #pragma unroll
        for (int ks = 0; ks < 4; ++ks)
            a[ks] = *(const bf16x8*)&sX[row][ks * 32 + kg * 8];
        #pragma unroll
        for (int f = 0; f < 8; ++f) {
            int o = w * 128 + f * 16 + row;       // h = w, d = f*16+row
            f32x4 acc = {0.f, 0.f, 0.f, 0.f};
            #pragma unroll
            for (int ks = 0; ks < 4; ++ks)
                acc = __builtin_amdgcn_mfma_f32_16x16x32_bf16(
                    a[ks], *(const bf16x8*)(wqb + (size_t)o * Dn + ks * 32 + kg * 8), acc, 0, 0, 0);
            float bias = bqs[o];
            #pragma unroll
            for (int rr = 0; rr < 4; ++rr)        // all 16 M-rows valid
                sQC[(kg * 4 + rr) * 1096 + w * 136 + f * 16 + row] = f2bf(acc[rr] + bias);
        }
    };

    // PV accumulate over slot rows [0, v) into c
    auto pv_acc = [&](float (&c)[Hn][2], int v) {
        #pragma unroll 2
        for (int l = 0; l < v; ++l) {
            unsigned nv = *(const unsigned*)&sN[w][l][2 * lane];
            float n0 = bf2f((unsigned short)(nv & 0xFFFFu));
            float n1 = bf2f((unsigned short)(nv >> 16));
            float4 p01 = *(const float4*)&sP[w][l][0];
            float4 p23 = *(const float4*)&sP[w][l][4];
            c[0][0] += p01.x * n0; c[0][1] += p01.x * n1;
            c[1][0] += p01.y * n0; c[1][1] += p01.y * n1;
            c[2][0] += p01.z * n0; c[2][1] += p01.z * n1;
            c[3][0] += p01.w * n0; c[3][1] += p01.w * n1;
            c[4][0] += p23.x * n0; c[4][1] += p23.x * n1;
            c[5][0] += p23.y * n0; c[5][1] += p23.y * n1;
            c[6][0] += p23.z * n0; c[6][1] += p23.z * n1;
            c[7][0] += p23.w * n0; c[7][1] += p23.w * n1;
        }
    };

    // 2-tile attention (wave-private, no max-subtraction, per-head sums)
    auto attn2 = [&](int node) {
        const int deg = sDeg[node];
        const int v0  = deg < 16 ? deg : 16;
        stage_half(node, 0, v0);

        const int hcol = row & 7;
        bf16x8 qf[4];
        #pragma unroll
        for (int ks = 0; ks < 4; ++ks)
            qf[ks] = *(const bf16x8*)&sQC[node * 1096 + hcol * 136 + ks * 32 + kg * 8];

        // tile A: slot rows 0..v0-1 (p = exp(s), masked rows -> 0)
        f32x4 s0 = {0.f,0.f,0.f,0.f};
        __builtin_amdgcn_s_setprio(1);
        #pragma unroll
        for (int ks = 0; ks < 4; ++ks)
            s0 = __builtin_amdgcn_mfma_f32_16x16x32_bf16(
                *(const bf16x8*)&sN[w][row][ks * 32 + kg * 8], qf[ks], s0, 0, 0, 0);
        __builtin_amdgcn_s_setprio(0);
        float sv[4];
        float sum = 0.f;                           // per-head (lane's column) sum
        #pragma unroll
        for (int j = 0; j < 4; ++j) {
            int l = kg * 4 + j;
            sv[j] = (l < v0) ? __expf(s0[j]) : 0.f;
            sum += sv[j];
        }
        sum += __shfl_xor(sum, 16);
        sum += __shfl_xor(sum, 32);
        if (row < 8) {
            #pragma unroll
            for (int j = 0; j < 4; ++j)
                sP[w][kg * 4 + j][row] = sv[j];
        }
        float c[Hn][2];
        #pragma unroll
        for (int h = 0; h < Hn; ++h) { c[h][0] = 0.f; c[h][1] = 0.f; }
        pv_acc(c, v0);

        if (deg > 16) {                            // tile B: global rows 16..deg-1
            const int v1 = deg - 16;
            stage_half(node, 16, v1);              // overwrite slot (same-wave DS order)
            f32x4 s1 = {0.f,0.f,0.f,0.f};
            __builtin_amdgcn_s_setprio(1);
            #pragma unroll
            for (int ks = 0; ks < 4; ++ks)
                s1 = __builtin_amdgcn_mfma_f32_16x16x32_bf16(
                    *(const bf16x8*)&sN[w][row][ks * 32 + kg * 8], qf[ks], s1, 0, 0, 0);
            __builtin_amdgcn_s_setprio(0);
            float sw[4];
            float sum1 = 0.f;
            #pragma unroll
            for (int j = 0; j < 4; ++j) {
                int l = kg * 4 + j;
                sw[j] = (l < v1) ? __expf(s1[j]) : 0.f;
                sum1 += sw[j];
            }
            sum1 += __shfl_xor(sum1, 16);
            sum1 += __shfl_xor(sum1, 32);
            sum += sum1;                           // no rescale: same (zero) shift
            if (row < 8) {
                #pragma unroll
                for (int j = 0; j < 4; ++j)
                    sP[w][kg * 4 + j][row] = sw[j];
            }
            pv_acc(c, v1);
        }

        // broadcast per-head sums; normalize each c[h] by ITS head's sum
        if (row < 8) sSum[w][row] = sum;           // 4 dup lanes write same value
        float4 r01 = *(const float4*)&sSum[w][0];
        float4 r23 = *(const float4*)&sSum[w][4];
        float rh[Hn] = {r01.x, r01.y, r01.z, r01.w, r23.x, r23.y, r23.z, r23.w};
        #pragma unroll
        for (int h = 0; h < Hn; ++h) {
            float inv = 1.f / rh[h];
            unsigned pk = (unsigned)f2bf(c[h][0] * inv) | ((unsigned)f2bf(c[h][1] * inv) << 16);
            *(unsigned*)&sQC[node * 1096 + h * 136 + 2 * lane] = pk;
        }
    };

    // ---- prologue ----
    if (t < 256) {
        int r = t >> 4, c = (t & 15) * 8;          // 16 rows x 16 chunks
        const float4* s = (const float4*)(nodeE + (size_t)(node0 + r) * Dn + c);
        *(bf16x8*)&sX[r][c] = cvt8(s[0], s[1]);
    }
    if (t < 16) sDeg[t] = degp[node0 + t];
    __syncthreads();

    // ======== layer 0 ========
    qgemm(wq0b, bq0s);
    __syncthreads();            // q visible

    attn2(w);                   // nodes 0..7   (wave-private, no barriers)
    attn2(8 + w);               // nodes 8..15
    __syncthreads();            // all c0 visible

    {   // ---- ep0: x1 = relu(x@wp0.T + c[h(d)]@wv0.T + b0); wave w owns d in [16w,16w+16)
        const int d = w * 16 + row;         // head h(d) = w
        f32x4 pa = {0.f,0.f,0.f,0.f}, va = {0.f,0.f,0.f,0.f};
        #pragma unroll
        for (int ks = 0; ks < 4; ++ks) {
            pa = __builtin_amdgcn_mfma_f32_16x16x32_bf16(
                a[ks], *(const bf16x8*)(wp0b + (size_t)d * Dn + ks * 32 + kg * 8), pa, 0, 0, 0);
            bf16x8 c0 = *(const bf16x8*)&sQC[row * 1096 + w * 136 + ks * 32 + kg * 8];
            va = __builtin_amdgcn_mfma_f32_16x16x32_bf16(
                c0, *(const bf16x8*)(wv0b + (size_t)d * Dn + ks * 32 + kg * 8), va, 0, 0, 0);
        }
        float bias = b0[d];
        #pragma unroll
        for (int rr = 0; rr < 4; ++rr)      // all 16 nodes
            sX[kg * 4 + rr][d] = f2bf(fmaxf(pa[rr] + va[rr] + bias, 0.f));
    }
    __syncthreads();            // new x visible

    // ======== layer 1 ========
    qgemm(wq1b, bq1s);
    __syncthreads();

    attn2(w);
    attn2(8 + w);
    __syncthreads();            // all c1 visible

    {   // ---- ep1: out = x1@wp1.T + (cflat@wv1'.T) + b1 (0.125 folded in wv1b/b1)
        const int d = w * 16 + row;
        f32x4 pa = {0.f,0.f,0.f,0.f};
        #pragma unroll
        for (int ks = 0; ks < 4; ++ks)
            pa = __builtin_amdgcn_mfma_f32_16x16x32_bf16(
                a[ks], *(const bf16x8*)(wp1b + (size_t)d * Dn + ks * 32 + kg * 8), pa, 0, 0, 0);
        f32x4 g = {0.f,0.f,0.f,0.f};
        #pragma unroll 8
        for (int ks2 = 0; ks2 < 32; ++ks2) {      // K = 1024 over hk
            int hk = ks2 * 32 + kg * 8;
            int h = hk >> 7, kk = hk & 127;
            bf16x8 c0 = *(const bf16x8*)&sQC[row * 1096 + h * 136 + kk];
            g = __builtin_amdgcn_mfma_f32_16x16x32_bf16(
                c0, *(const bf16x8*)(wv1b + ((size_t)(h * Dn + d)) * Dn + kk), g, 0, 0, 0);
        }
        float bias = b1[d];
        #pragma unroll
        for (int rr = 0; rr < 4; ++rr)
            out[(size_t)(node0 + kg * 4 + rr) * Dn + d] = pa[rr] + g[rr] + bias;
    }
}

// ================= fallback (ws-independent raw-pointer kernel) ===================
__global__ __launch_bounds__(256, 2)
void gcn2(const float* __restrict__ nodeE, const float* __restrict__ neighE,
          const int* __restrict__ degp,
          const float* __restrict__ wq0, const float* __restrict__ bq0,
          const float* __restrict__ wv0, const float* __restrict__ bv0,
          const float* __restrict__ wp0, const float* __restrict__ bp0,
          const float* __restrict__ wq1, const float* __restrict__ bq1,
          const float* __restrict__ wv1, const float* __restrict__ bv1,
          const float* __restrict__ wp1, const float* __restrict__ bp1,
          float* __restrict__ out)
{
    __shared__ unsigned short sX[16][Dn];
    __shared__ unsigned short sQ[8][Hn][Dn];
    __shared__ unsigned short sN[4][Ln][Dn + 8];
    __shared__ float          sP[4][Hn][Ln];
    __shared__ unsigned short sC[8][Hn][Dn + 8];
    __shared__ int            sDeg[8];

    const int t    = threadIdx.x;
    const int lane = t & 63;
    const int w    = t >> 6;
    const int row  = lane & 15;
    const int kg   = lane >> 4;
    const int node0 = blockIdx.x * 8;
    const float scale = 0.08838834764831845f;

    {
        int i = t * 8, r = i >> 7, c = i & 127;
        if (r < 8) {
            const float4* s = (const float4*)(nodeE + (size_t)(node0 + r) * Dn + c);
            *(bf16x8*)&sX[r][c] = cvt8(s[0], s[1]);
        } else {
            bf16x8 z = {0,0,0,0,0,0,0,0};
            *(bf16x8*)&sX[r][c] = z;
        }
        if (t < 8) sDeg[t] = degp[node0 + t];
    }
    __syncthreads();

    auto qgemm = [&](const float* wq, const float* bq) {
        bf16x8 a[4];
        #pragma unroll
        for (int ks = 0; ks < 4; ++ks)
            a[ks] = *(const bf16x8*)&sX[row][ks*32 + kg*8];
        for (int f = 0; f < 16; ++f) {
            int o = w*256 + f*16 + row;
            f32x4 acc = {0.f, 0.f, 0.f, 0.f};
            #pragma unroll
            for (int ks = 0; ks < 4; ++ks) {
                const float4* wp4 = (const float4*)(wq + (size_t)o*Dn + ks*32 + kg*8);
                acc = __builtin_amdgcn_mfma_f32_16x16x32_bf16(a[ks], cvt8(wp4[0], wp4[1]), acc, 0, 0, 0);
            }
            float bias = bq[o];
            if (kg < 2) {
                #pragma unroll
                for (int rr = 0; rr < 4; ++rr) {
                    int nd = kg*4 + rr;
                    sQ[nd][o >> 7][o & 127] = f2bf((acc[rr] + bias) * scale);
                }
            }
        }
    };

    auto attn = [&](int b) {
        #pragma unroll
        for (int it = 0; it < 8; ++it) {
            int e8 = t + 256 * it;
            int n = e8 >> 9, l = (e8 >> 4) & 31, d8 = e8 & 15;
            const float4* s = (const float4*)(neighE + ((size_t)(node0 + b*4 + n)*Ln + l)*Dn + d8*8);
            *(bf16x8*)&sN[n][l][d8*8] = cvt8(s[0], s[1]);
        }
        __syncthreads();

        const int deg  = sDeg[b*4 + w];
        const int hcol = row & 7;
        bf16x8 qf[4];
        #pragma unroll
        for (int ks = 0; ks < 4; ++ks)
            qf[ks] = *(const bf16x8*)&sQ[b*4 + w][hcol][ks*32 + kg*8];

        f32x4 s0 = {0.f,0.f,0.f,0.f}, s1 = {0.f,0.f,0.f,0.f};
        #pragma unroll
        for (int ks = 0; ks < 4; ++ks) {
            bf16x8 a0 = *(const bf16x8*)&sN[w][row][ks*32 + kg*8];
            bf16x8 a1 = *(const bf16x8*)&sN[w][16 + row][ks*32 + kg*8];
            s0 = __builtin_amdgcn_mfma_f32_16x16x32_bf16(a0, qf[ks], s0, 0, 0, 0);
            s1 = __builtin_amdgcn_mfma_f32_16x16x32_bf16(a1, qf[ks], s1, 0, 0, 0);
        }
        float sv[8];
        #pragma unroll
        for (int rr = 0; rr < 4; ++rr) { sv[rr] = s0[rr]; sv[4+rr] = s1[rr]; }
        float m = -3.0e38f;
        #pragma unroll
        for (int j = 0; j < 8; ++j) {
            int l = (j >> 2)*16 + kg*4 + (j & 3);
            if (l >= deg) sv[j] = -3.0e38f;
            m = fmaxf(m, sv[j]);
        }
        m = fmaxf(m, __shfl_xor(m, 16));
        m = fmaxf(m, __shfl_xor(m, 32));
        float sum = 0.f;
        #pragma unroll
        for (int j = 0; j < 8; ++j) {
            float e = (sv[j] > -1.0e38f) ? __expf(sv[j] - m) : 0.f;
            sv[j] = e; sum += e;
        }
        sum += __shfl_xor(sum, 16);
        sum += __shfl_xor(sum, 32);
        float rinv = 1.f / sum;
        if (row < 8) {
            #pragma unroll
            for (int j = 0; j < 8; ++j) {
                int l = (j >> 2)*16 + kg*4 + (j & 3);
                sP[w][row][l] = sv[j] * rinv;
            }
        }

        float c[Hn][2];
        #pragma unroll
        for (int h = 0; h < Hn; ++h) { c[h][0] = 0.f; c[h][1] = 0.f; }
        #pragma unroll 4
        for (int l = 0; l < Ln; ++l) {
            unsigned nv = *(const unsigned*)&sN[w][l][2*lane];
            float n0 = bf2f((unsigned short)(nv & 0xFFFFu));
            float n1 = bf2f((unsigned short)(nv >> 16));
            #pragma unroll
            for (int h = 0; h < Hn; ++h) {
                float p = sP[w][h][l];
                c[h][0] += p * n0; c[h][1] += p * n1;
            }
        }
        #pragma unroll
        for (int h = 0; h < Hn; ++h) {
            unsigned pk = (unsigned)f2bf(c[h][0]) | ((unsigned)f2bf(c[h][1]) << 16);
            *(unsigned*)&sC[b*4 + w][h][2*lane] = pk;
        }
        __syncthreads();
    };

    auto ep0 = [&]() {
        bf16x8 a1[4];
        #pragma unroll
        for (int ks = 0; ks < 4; ++ks)
            a1[ks] = *(const bf16x8*)&sX[row][ks*32 + kg*8];
        float xn[2][4]; int dd[2];
        #pragma unroll
        for (int fi = 0; fi < 2; ++fi) {
            int f = 2*w + fi;
            int d = f*16 + row; dd[fi] = d;
            f32x4 acc = {0.f,0.f,0.f,0.f}, acc2 = {0.f,0.f,0.f,0.f};
            #pragma unroll
            for (int ks = 0; ks < 4; ++ks) {
                const float4* bp = (const float4*)(wp0 + (size_t)d*Dn + ks*32 + kg*8);
                acc = __builtin_amdgcn_mfma_f32_16x16x32_bf16(a1[ks], cvt8(bp[0], bp[1]), acc, 0, 0, 0);
                bf16x8 a2 = *(const bf16x8*)&sC[row & 7][f][ks*32 + kg*8];
                const float4* vp = (const float4*)(wv0 + (size_t)d*Dn + ks*32 + kg*8);
                acc2 = __builtin_amdgcn_mfma_f32_16x16x32_bf16(a2, cvt8(vp[0], vp[1]), acc2, 0, 0, 0);
            }
            float bias = bp0[d] + bv0[d];
            #pragma unroll
            for (int rr = 0; rr < 4; ++rr)
                xn[fi][rr] = fmaxf(acc[rr] + acc2[rr] + bias, 0.f);
        }
        __syncthreads();
        if (kg < 2) {
            #pragma unroll
            for (int fi = 0; fi < 2; ++fi)
                #pragma unroll
                for (int rr = 0; rr < 4; ++rr)
                    sX[kg*4 + rr][dd[fi]] = f2bf(xn[fi][rr]);
        }
        __syncthreads();
    };

    auto ep1 = [&]() {
        bf16x8 a1[4];
        #pragma unroll
        for (int ks = 0; ks < 4; ++ks)
            a1[ks] = *(const bf16x8*)&sX[row][ks*32 + kg*8];
        #pragma unroll
        for (int fi = 0; fi < 2; ++fi) {
            int f = 2*w + fi;
            int d = f*16 + row;
            f32x4 acc = {0.f,0.f,0.f,0.f};
            #pragma unroll
            for (int ks = 0; ks < 4; ++ks) {
                const float4* bp = (const float4*)(wp1 + (size_t)d*Dn + ks*32 + kg*8);
                acc = __builtin_amdgcn_mfma_f32_16x16x32_bf16(a1[ks], cvt8(bp[0], bp[1]), acc, 0, 0, 0);
            }
            f32x4 acc2 = {0.f,0.f,0.f,0.f};
            for (int ks2 = 0; ks2 < 32; ++ks2) {
                int hk = ks2*32 + kg*8;
                int h = hk >> 7, kk = hk & 127;
                bf16x8 a2 = *(const bf16x8*)&sC[row & 7][h][kk];
                const float4* vp = (const float4*)(wv1 + ((size_t)(h*Dn + d))*Dn + kk);
                acc2 = __builtin_amdgcn_mfma_f32_16x16x32_bf16(a2, cvt8(vp[0], vp[1]), acc2, 0, 0, 0);
            }
            float bsum = 0.f;
            #pragma unroll
            for (int h = 0; h < Hn; ++h) bsum += bv1[h*Dn + d];
            float bias = bp1[d] + 0.125f * bsum;
            if (kg < 2) {
                #pragma unroll
                for (int rr = 0; rr < 4; ++rr) {
                    int nd = kg*4 + rr;
                    out[(size_t)(node0 + nd)*Dn + d] = acc[rr] + 0.125f*acc2[rr] + bias;
                }
            }
        }
    };

    qgemm(wq0, bq0);
    __syncthreads();
    attn(0);
    attn(1);
    ep0();
    qgemm(wq1, bq1);
    __syncthreads();
    attn(0);
    attn(1);
    ep1();
}

extern "C" void kernel_launch(void* const* d_in, const int* in_sizes, int n_in,
                              void* d_out, int out_size, void* d_ws, size_t ws_size,
                              hipStream_t stream) {
    const float* nodeE  = (const float*)d_in[0];
    const float* neighE = (const float*)d_in[1];
    const int*   degp   = (const int*)d_in[2];
    const float* wq0 = (const float*)d_in[3];
    const float* bq0 = (const float*)d_in[4];
    const float* wv0 = (const float*)d_in[5];
    const float* bv0 = (const float*)d_in[6];
    const float* wp0 = (const float*)d_in[7];
    const float* bp0 = (const float*)d_in[8];
    const float* wq1 = (const float*)d_in[9];
    const float* bq1 = (const float*)d_in[10];
    const float* wv1 = (const float*)d_in[11];
    const float* bv1 = (const float*)d_in[12];
    const float* wp1 = (const float*)d_in[13];
    const float* bp1 = (const float*)d_in[14];
    float* outp = (float*)d_out;

    if (ws_size >= WS_NEED) {
        unsigned short* ws = (unsigned short*)d_ws;
        hipLaunchKernelGGL(cvt_weights, dim3((CVT_ITEMS + 255) / 256), dim3(256), 0, stream,
                           wq0, bq0, wv0, bv0, wp0, bp0,
                           wq1, bq1, wv1, bv1, wp1, bp1, ws);
        hipLaunchKernelGGL(gcn15, dim3(512), dim3(512), 0, stream,
                           nodeE, neighE, degp, ws, outp);
    } else {
        hipLaunchKernelGGL(gcn2, dim3(1024), dim3(256), 0, stream,
                           nodeE, neighE, degp,
                           wq0, bq0, wv0, bv0, wp0, bp0,
                           wq1, bq1, wv1, bv1, wp1, bp1, outp);
    }
}